// Round 1
// baseline (70.030 us; speedup 1.0000x reference)
//
#include <hip/hip_runtime.h>
#include <math.h>

#ifndef M_PI
#define M_PI 3.14159265358979323846
#endif

#define NSIDE  128
#define NTHETA 511            // = LMAX = number of rings
#define MMAX   257
#define NPIX   196608

// Kernel 1: ftm[k][m] = sum_l x[l][m] * pct[m][l][k]
// One block per (k-chunk, m). Threads = contiguous k -> coalesced pct loads.
__global__ __launch_bounds__(256)
void ftm_kernel(const float* __restrict__ x_re,
                const float* __restrict__ x_im,
                const float* __restrict__ pct,
                float* __restrict__ ftm_re,
                float* __restrict__ ftm_im)
{
    __shared__ float xr[NTHETA];
    __shared__ float xi[NTHETA];
    const int m   = blockIdx.y;
    const int tid = threadIdx.x;
    for (int i = tid; i < NTHETA; i += 256) {
        xr[i] = x_re[(size_t)i * MMAX + m];
        xi[i] = x_im[(size_t)i * MMAX + m];
    }
    __syncthreads();
    const int k = blockIdx.x * 256 + tid;
    if (k >= NTHETA) return;

    const float* p = pct + (size_t)m * NTHETA * NTHETA + k;
    float ar = 0.f, ai = 0.f;
    int l = 0;
    for (; l <= NTHETA - 8; l += 8) {
        float v[8];
        #pragma unroll
        for (int u = 0; u < 8; ++u) v[u] = p[(size_t)(l + u) * NTHETA];
        #pragma unroll
        for (int u = 0; u < 8; ++u) {
            ar = fmaf(xr[l + u], v[u], ar);
            ai = fmaf(xi[l + u], v[u], ai);
        }
    }
    for (; l < NTHETA; ++l) {
        float v = p[(size_t)l * NTHETA];
        ar = fmaf(xr[l], v, ar);
        ai = fmaf(xi[l], v, ai);
    }
    ftm_re[(size_t)k * MMAX + m] = ar;
    ftm_im[(size_t)k * MMAX + m] = ai;
}

// Kernel 2: direct inverse rFFT per ring at pixel azimuths.
// f[cum+k] = fr[0] + 2*sum_{m=1}^{N/2-1} (fr[m]*cos(m*phi) - fi[m]*sin(m*phi))
//                  +     (fr[N/2]*cos(..) - fi[N/2]*sin(..))
// with phi = phi0(t) + 2*pi*k/nphi  (per-ring phase shift folded in).
__global__ __launch_bounds__(256)
void ring_kernel(const float* __restrict__ ftm_re,
                 const float* __restrict__ ftm_im,
                 float* __restrict__ out)
{
    const int t = blockIdx.y;
    int nphi, cum;
    double phi0;
    if (t < NSIDE - 1) {                       // north polar cap
        nphi = 4 * (t + 1);
        cum  = 2 * t * (t + 1);
        phi0 = M_PI / (4.0 * (t + 1));
    } else if (t <= 3 * NSIDE - 1) {           // equatorial belt
        nphi = 4 * NSIDE;
        cum  = 2 * (NSIDE - 1) * NSIDE + (t - (NSIDE - 1)) * 4 * NSIDE;
        phi0 = (M_PI / (2.0 * NSIDE)) * (0.5 * (double)((t - NSIDE + 2) % 2));
    } else {                                   // south polar cap
        int s = 4 * NSIDE - 1 - t;
        nphi = 4 * s;
        cum  = NPIX - 2 * s * (s + 1);
        phi0 = M_PI / (4.0 * s);
    }
    if ((int)blockIdx.x * 256 >= nphi) return;  // block-uniform early exit

    const int mtop = nphi / 2;                  // inclusive top harmonic (<= 256)
    __shared__ float fr[MMAX];
    __shared__ float fi[MMAX];
    for (int i = threadIdx.x; i <= mtop; i += 256) {
        fr[i] = ftm_re[(size_t)t * MMAX + i];
        fi[i] = ftm_im[(size_t)t * MMAX + i];
    }
    __syncthreads();

    const int k = blockIdx.x * 256 + threadIdx.x;
    if (k >= nphi) return;

    double phi = phi0 + (2.0 * M_PI) * ((double)k / (double)nphi);
    float sp, cp;
    sincosf((float)phi, &sp, &cp);

    float cr = 1.f, ci = 0.f;                   // e^{i*m*phi}, m=0
    float acc = fr[0];
    for (int m = 1; m < mtop; ++m) {
        float nr = cr * cp - ci * sp;
        float ni = cr * sp + ci * cp;
        cr = nr; ci = ni;
        acc += 2.f * (fr[m] * cr - fi[m] * ci);
    }
    {   // m = mtop, weight 1
        float nr = cr * cp - ci * sp;
        float ni = cr * sp + ci * cp;
        acc += fr[mtop] * nr - fi[mtop] * ni;
    }
    out[cum + k] = acc;
}

extern "C" void kernel_launch(void* const* d_in, const int* in_sizes, int n_in,
                              void* d_out, int out_size, void* d_ws, size_t ws_size,
                              hipStream_t stream)
{
    const float* x_re = (const float*)d_in[0];
    const float* x_im = (const float*)d_in[1];
    const float* pct  = (const float*)d_in[2];
    float* out = (float*)d_out;

    float* ftm_re = (float*)d_ws;                       // NTHETA*MMAX floats
    float* ftm_im = ftm_re + (size_t)NTHETA * MMAX;     // NTHETA*MMAX floats

    ftm_kernel<<<dim3(2, MMAX), 256, 0, stream>>>(x_re, x_im, pct, ftm_re, ftm_im);
    ring_kernel<<<dim3(2, NTHETA), 256, 0, stream>>>(ftm_re, ftm_im, out);
}